// Round 9
// baseline (2418.650 us; speedup 1.0000x reference)
//
#include <hip/hip_runtime.h>

typedef unsigned int uint;
typedef _Float16 f16;
typedef _Float16 f16x2 __attribute__((ext_vector_type(2)));
typedef _Float16 f16x4 __attribute__((ext_vector_type(4)));
typedef _Float16 f16x8 __attribute__((ext_vector_type(8)));
typedef float f32x4 __attribute__((ext_vector_type(4)));

#define B_ 64
#define T_ 1024
#define I_ 128
#define H_ 256

// ---------------- prep: transpose x-part weights to [512 cols][K] fp16 ----------------
template<int KIN>
__global__ void prep_wxt(const float* __restrict__ Wf, const float* __restrict__ Wc,
                         f16* __restrict__ WxT) {
  int o = blockIdx.x * 256 + threadIdx.x;
  if (o >= 512 * KIN) return;
  int n = o / KIN, k = o % KIN;
  float v = (n < 256) ? Wf[k * H_ + n] : Wc[k * H_ + (n - 256)];
  WxT[o] = (f16)v;
}

// ---------------- prep: transpose recurrent weights to UT[512 n][256 k] fp16 ----------
__global__ void prep_ut(const float* __restrict__ Wf, const float* __restrict__ Wc,
                        f16* __restrict__ UT, int DIN) {
  int o = blockIdx.x * 256 + threadIdx.x;   // 512*256 = 131072
  int n = o >> 8, k = o & 255;
  const float* W = (n < 256) ? Wf : Wc;
  UT[o] = (f16)W[(DIN + k) * H_ + (n & 255)];
}

// ---------------- zero the sync counters (progress[4] + done[4][8]) -------------------
__global__ void init_sync(int* s) { if (threadIdx.x < 36) s[threadIdx.x] = 0; }

// ---------------- x-part GEMM (layer 1, fp32 A): Xg[m][512] = x @ Wx1T^T + bias -------
template<int KFULL, bool AF32>
__global__ __launch_bounds__(256) void gemm_xpart(const void* __restrict__ Av,
    const f16* __restrict__ Bt, const float* __restrict__ bf, const float* __restrict__ bc,
    f16* __restrict__ Xg) {
  __shared__ __align__(16) f16 As[128][72];
  __shared__ __align__(16) f16 Bs[128][72];
  const int m0 = blockIdx.x * 128, n0 = blockIdx.y * 128;
  const int tid = threadIdx.x, lane = tid & 63, wid = tid >> 6;
  const int wr = wid >> 1, wc = wid & 1;
  f32x4 zero4 = {0.f, 0.f, 0.f, 0.f};
  f32x4 acc[4][4];
  #pragma unroll
  for (int i = 0; i < 4; ++i)
    #pragma unroll
    for (int j = 0; j < 4; ++j) acc[i][j] = zero4;
  const int r2 = tid >> 1, hh = tid & 1;
  for (int kb = 0; kb < KFULL / 64; ++kb) {
    const int k0 = kb * 64;
    if (kb) __syncthreads();
    if (AF32) {
      const float* A = (const float*)Av;
      const float* src = A + (size_t)(m0 + r2) * KFULL + k0 + hh * 32;
      #pragma unroll
      for (int i = 0; i < 8; ++i) {
        float4 v = *(const float4*)(src + i * 4);
        f16x4 p = { (f16)v.x, (f16)v.y, (f16)v.z, (f16)v.w };
        *(f16x4*)&As[r2][hh * 32 + i * 4] = p;
      }
    } else {
      const f16* A = (const f16*)Av;
      const f16* src = A + (size_t)(m0 + r2) * KFULL + k0 + hh * 32;
      #pragma unroll
      for (int i = 0; i < 4; ++i)
        *(uint4*)&As[r2][hh * 32 + i * 8] = *(const uint4*)(src + i * 8);
    }
    {
      const f16* src = Bt + (size_t)(n0 + r2) * KFULL + k0 + hh * 32;
      #pragma unroll
      for (int i = 0; i < 4; ++i)
        *(uint4*)&Bs[r2][hh * 32 + i * 8] = *(const uint4*)(src + i * 8);
    }
    __syncthreads();
    #pragma unroll
    for (int kt = 0; kt < 2; ++kt) {
      f16x8 af[4], bfr[4];
      #pragma unroll
      for (int i = 0; i < 4; ++i)
        af[i] = *(const f16x8*)&As[wr * 64 + i * 16 + (lane & 15)][kt * 32 + (lane >> 4) * 8];
      #pragma unroll
      for (int j = 0; j < 4; ++j)
        bfr[j] = *(const f16x8*)&Bs[wc * 64 + j * 16 + (lane & 15)][kt * 32 + (lane >> 4) * 8];
      #pragma unroll
      for (int i = 0; i < 4; ++i)
        #pragma unroll
        for (int j = 0; j < 4; ++j)
          acc[i][j] = __builtin_amdgcn_mfma_f32_16x16x32_f16(af[i], bfr[j], acc[i][j], 0, 0, 0);
    }
  }
  const float* bias = (n0 < 256) ? bf : bc;
  #pragma unroll
  for (int j = 0; j < 4; ++j) {
    const int gn = n0 + wc * 64 + j * 16 + (lane & 15);
    const float bv = bias[gn & 255];
    #pragma unroll
    for (int i = 0; i < 4; ++i) {
      #pragma unroll
      for (int reg = 0; reg < 4; ++reg) {
        const int gm = m0 + wr * 64 + i * 16 + (lane >> 4) * 4 + reg;
        Xg[(size_t)gm * 512 + gn] = (f16)(acc[i][j][reg] + bv);
      }
    }
  }
}

// ---------------- device: one 128x128 Xg2 GEMM tile, ALL 8 waves active ---------------
// A = y1h (f16, K=256), B = Wx2T.  Wave grid 2x4: wrow=wid>>2 (64-row half),
// wcol=wid&3 (32-col quarter).  Per wave: 4 m-frags x 2 n-frags x 2 kt = 16 MFMAs.
// (R8 ran this with 4 active waves of 8 -> 2x slower tiles; worker tile latency
// sat directly on L2-rec's critical path via the JIT chunk gate.)
__device__ __forceinline__ void gemm_tile_l2(const f16* __restrict__ A,
    const f16* __restrict__ Bt, const float* __restrict__ bf, const float* __restrict__ bc,
    f16* __restrict__ Xg, int m0, int n0, f16 (*As)[72], f16 (*Bs)[72]) {
  const int tid = threadIdx.x, lane = tid & 63, wid = tid >> 6;
  const int wrow = wid >> 2, wcol = wid & 3;
  f32x4 zero4 = {0.f, 0.f, 0.f, 0.f};
  f32x4 acc[4][2];
  #pragma unroll
  for (int i = 0; i < 4; ++i)
    #pragma unroll
    for (int j = 0; j < 2; ++j) acc[i][j] = zero4;
  const int row = tid >> 2, q = tid & 3;   // 512 threads: 128 rows x 4 slices of 16 f16
  for (int kb = 0; kb < 4; ++kb) {
    const int k0 = kb * 64;
    if (kb) __syncthreads();
    {
      const f16* srcA = A + (size_t)(m0 + row) * 256 + k0 + q * 16;
      *(uint4*)&As[row][q * 16 + 0] = *(const uint4*)(srcA + 0);
      *(uint4*)&As[row][q * 16 + 8] = *(const uint4*)(srcA + 8);
      const f16* srcB = Bt + (size_t)(n0 + row) * 256 + k0 + q * 16;
      *(uint4*)&Bs[row][q * 16 + 0] = *(const uint4*)(srcB + 0);
      *(uint4*)&Bs[row][q * 16 + 8] = *(const uint4*)(srcB + 8);
    }
    __syncthreads();
    #pragma unroll
    for (int kt = 0; kt < 2; ++kt) {
      f16x8 af[4], bfr[2];
      #pragma unroll
      for (int i = 0; i < 4; ++i)
        af[i] = *(const f16x8*)&As[wrow * 64 + i * 16 + (lane & 15)][kt * 32 + (lane >> 4) * 8];
      #pragma unroll
      for (int j = 0; j < 2; ++j)
        bfr[j] = *(const f16x8*)&Bs[wcol * 32 + j * 16 + (lane & 15)][kt * 32 + (lane >> 4) * 8];
      #pragma unroll
      for (int i = 0; i < 4; ++i)
        #pragma unroll
        for (int j = 0; j < 2; ++j)
          acc[i][j] = __builtin_amdgcn_mfma_f32_16x16x32_f16(af[i], bfr[j], acc[i][j], 0, 0, 0);
    }
  }
  const float* bias = (n0 < 256) ? bf : bc;
  #pragma unroll
  for (int j = 0; j < 2; ++j) {
    const int gn = n0 + wcol * 32 + j * 16 + (lane & 15);
    const float bv = bias[gn & 255];
    #pragma unroll
    for (int i = 0; i < 4; ++i) {
      #pragma unroll
      for (int reg = 0; reg < 4; ++reg) {
        const int gm = m0 + wrow * 64 + i * 16 + (lane >> 4) * 4 + reg;
        Xg[(size_t)gm * 512 + gn] = (f16)(acc[i][j][reg] + bv);
      }
    }
  }
  __syncthreads();   // As/Bs safe for next tile
}

// ---------------- device: R6 rec inner loop + optional publish/gate -------------------
// 8 waves; wave w owns f-tiles n={32w,32w+16}, c-tiles +256.  Weights 128 VGPR/AGPR.
// h[16][256] f16 in LDS (pitch 264), double-buffered; one lgkm-only barrier/step.
// prog_pub (L1 role): publish t+1 every 32 steps (agent-release after vmcnt drain).
// done_gate (L2 role): before consuming Xg chunk c (128 steps), wait done[c]==64.
__device__ __forceinline__ void rec_core(const f16* __restrict__ UT,
    f16* __restrict__ Xg, float* __restrict__ yf, f16* __restrict__ yh,
    float* __restrict__ hid, const int g, int* prog_pub, int* done_gate,
    f16 (*hbuf)[16][264]) {
  const int tid = threadIdx.x;
  const int lane = tid & 63, w = tid >> 6;
  const int lr = lane & 15, lg = lane >> 4;
  const int m0 = g * 16;

  const int nt[4] = { 32 * w, 32 * w + 16, 256 + 32 * w, 256 + 32 * w + 16 };

  f16x8 uw[4][8];
  #pragma unroll
  for (int tt = 0; tt < 4; ++tt)
    #pragma unroll
    for (int kf = 0; kf < 8; ++kf)
      uw[tt][kf] = *(const f16x8*)&UT[(size_t)(nt[tt] + lr) * 256 + kf * 32 + lg * 8];
  #pragma unroll
  for (int tt = 0; tt < 4; ++tt)
    #pragma unroll
    for (int kf = 0; kf < 8; ++kf)
      asm volatile("" : "+v"(uw[tt][kf]));

  {
    uint* hz = (uint*)&hbuf[0][0][0];
    for (int i = tid; i < 2112; i += 512) hz[i] = 0u;
  }

  // L2 role: Xg chunk 0 must be written before the first reads
  if (done_gate) {
    if (tid == 0)
      while (__hip_atomic_load(&done_gate[0], __ATOMIC_ACQUIRE, __HIP_MEMORY_SCOPE_AGENT) < 64)
        __builtin_amdgcn_s_sleep(8);
    __syncthreads();
  }

  const f16* xp[4];
  #pragma unroll
  for (int tt = 0; tt < 4; ++tt)
    xp[tt] = Xg + ((size_t)(m0 + lr) * T_) * 512 + nt[tt] + 4 * lg;

  float hreg[2][4] = {{0.f,0.f,0.f,0.f},{0.f,0.f,0.f,0.f}};
  f16x4 xcur[4];
  #pragma unroll
  for (int tt = 0; tt < 4; ++tt) xcur[tt] = *(const f16x4*)xp[tt];

  const size_t ybase = (size_t)(m0 + lr) * T_ * H_;
  const int ycol0 = 32 * w + 4 * lg;

  __syncthreads();

  #pragma unroll 1
  for (int t = 0; t < T_; ++t) {
    // L2 role: gate the NEXT chunk before prefetching into it
    if (done_gate) {
      const int tp1 = t + 1;
      if ((tp1 & 127) == 0 && (tp1 >> 7) < 8) {
        if (tid == 0)
          while (__hip_atomic_load(&done_gate[tp1 >> 7], __ATOMIC_ACQUIRE, __HIP_MEMORY_SCOPE_AGENT) < 64)
            __builtin_amdgcn_s_sleep(8);
        __syncthreads();
      }
    }

    const int tn = (t + 1 < T_) ? t + 1 : t;
    f16x4 xn[4];
    #pragma unroll
    for (int tt = 0; tt < 4; ++tt) xn[tt] = *(const f16x4*)(xp[tt] + (size_t)tn * 512);

    const f16* hrow = &hbuf[t & 1][lr][0];
    f16x8 hf[8];
    #pragma unroll
    for (int kf = 0; kf < 8; ++kf)
      hf[kf] = *(const f16x8*)(hrow + kf * 32 + lg * 8);

    f32x4 acc[4];
    #pragma unroll
    for (int tt = 0; tt < 4; ++tt) acc[tt] = (f32x4){0.f, 0.f, 0.f, 0.f};
    #pragma unroll
    for (int kf = 0; kf < 8; ++kf)
      #pragma unroll
      for (int tt = 0; tt < 4; ++tt)
        acc[tt] = __builtin_amdgcn_mfma_f32_16x16x32_f16(uw[tt][kf], hf[kf], acc[tt], 0, 0, 0);

    f16x4 hn4[2];
    #pragma unroll
    for (int p = 0; p < 2; ++p) {
      #pragma unroll
      for (int r = 0; r < 4; ++r) {
        float pf = acc[p][r]     + (float)xcur[p][r];
        float pc = acc[2 + p][r] + (float)xcur[2 + p][r];
        float fg = __builtin_amdgcn_rcpf(1.f + __expf(-pf));
        float e2 = __expf(2.f * pc);
        float cc = 1.f - 2.f * __builtin_amdgcn_rcpf(e2 + 1.f);
        float hn = cc + fg * (hreg[p][r] - cc);
        hreg[p][r] = hn;
        hn4[p][r] = (f16)hn;
      }
      *(f16x4*)&hbuf[(t + 1) & 1][lr][ycol0 + 16 * p] = hn4[p];
    }
    if (yh) {
      #pragma unroll
      for (int p = 0; p < 2; ++p)
        *(f16x4*)(yh + ybase + (size_t)t * H_ + ycol0 + 16 * p) = hn4[p];
    }
    if (yf) {
      #pragma unroll
      for (int p = 0; p < 2; ++p) {
        float4 yv = make_float4(hreg[p][0], hreg[p][1], hreg[p][2], hreg[p][3]);
        *(float4*)(yf + ybase + (size_t)t * H_ + ycol0 + 16 * p) = yv;
      }
    }
    if (t == T_ - 1) {
      #pragma unroll
      for (int p = 0; p < 2; ++p) {
        float4 hv = make_float4(hreg[p][0], hreg[p][1], hreg[p][2], hreg[p][3]);
        *(float4*)(hid + (size_t)(m0 + lr) * H_ + ycol0 + 16 * p) = hv;
      }
    }

    asm volatile("s_waitcnt lgkmcnt(0)" ::: "memory");
    __builtin_amdgcn_s_barrier();
    asm volatile("" ::: "memory");

    // L1 role: publish progress (y1h through step t now globally visible)
    if (prog_pub && ((t & 31) == 31)) {
      asm volatile("s_waitcnt vmcnt(0)" ::: "memory");
      __syncthreads();
      if (tid == 0)
        __hip_atomic_store(prog_pub, t + 1, __ATOMIC_RELEASE, __HIP_MEMORY_SCOPE_AGENT);
    }

    #pragma unroll
    for (int tt = 0; tt < 4; ++tt) xcur[tt] = xn[tt];
  }
}

// ---------------- fused pipeline: 4 L1-rec + 128 GEMM workers + 4 L2-rec --------------
// DAG: L1 -> (progress[g]) -> workers -> (done[g][c]) -> L2.  136 blocks < 256 CUs ->
// all resident, no circular waits.  Workers overwrite Xg IN PLACE with Xg2: tile
// (b, chunk c) is only written once progress[b>>4] >= 128(c+1), i.e. L1 has consumed
// (and prefetched past) those rows.  128 workers x 2 tiles/chunk (vs R8's 64 x 4):
// per-chunk worker latency ~4x lower -> L2's JIT gate stalls shrink ~250 us.
__global__ __launch_bounds__(512, 1) void fused(const f16* __restrict__ UT1,
    const f16* __restrict__ UT2, f16* __restrict__ Xg, const f16* __restrict__ Wx2T,
    const float* __restrict__ bf2, const float* __restrict__ bc2,
    f16* __restrict__ y1h, float* __restrict__ y2,
    float* __restrict__ hid1, float* __restrict__ hid2, int* __restrict__ sync) {
  __shared__ __align__(16) f16 hbuf[2][16][264];
  __shared__ __align__(16) f16 As[128][72];
  __shared__ __align__(16) f16 Bs[128][72];
  int* prog = sync;        // [4]  L1 step progress per row-group
  int* done = sync + 4;    // [4][8] finished Xg2 tiles per (group, t-chunk), target 64
  const int bid = blockIdx.x, tid = threadIdx.x;

  if (bid < 4) {
    rec_core(UT1, Xg, nullptr, y1h, hid1, bid, &prog[bid], nullptr, hbuf);
  } else if (bid < 132) {
    const int wk = bid - 4;                        // 0..127
    for (int j = 0; j < 16; ++j) {
      const int tau = wk + 128 * j;                // chunk-major tile order
      const int c = tau >> 8, rem = tau & 255, b = rem >> 2, n = rem & 3;
      const int g1 = b >> 4;
      if (tid == 0)
        while (__hip_atomic_load(&prog[g1], __ATOMIC_ACQUIRE, __HIP_MEMORY_SCOPE_AGENT) < c * 128 + 128)
          __builtin_amdgcn_s_sleep(8);
      __syncthreads();
      gemm_tile_l2(y1h, Wx2T, bf2, bc2, Xg, b * 1024 + c * 128, n * 128, As, Bs);
      asm volatile("s_waitcnt vmcnt(0)" ::: "memory");
      __syncthreads();
      if (tid == 0)
        __hip_atomic_fetch_add(&done[g1 * 8 + c], 1, __ATOMIC_ACQ_REL, __HIP_MEMORY_SCOPE_AGENT);
    }
  } else {
    const int g = bid - 132;
    rec_core(UT2, Xg, y2, nullptr, hid2, g, nullptr, &done[g * 8], hbuf);
  }
}

extern "C" void kernel_launch(void* const* d_in, const int* in_sizes, int n_in,
                              void* d_out, int out_size, void* d_ws, size_t ws_size,
                              hipStream_t stream) {
  (void)in_sizes; (void)n_in; (void)out_size; (void)ws_size;
  const float* x   = (const float*)d_in[0];
  const float* Wf1 = (const float*)d_in[1];
  const float* bf1 = (const float*)d_in[2];
  const float* Wc1 = (const float*)d_in[3];
  const float* bc1 = (const float*)d_in[4];
  const float* Wf2 = (const float*)d_in[5];
  const float* bf2 = (const float*)d_in[6];
  const float* Wc2 = (const float*)d_in[7];
  const float* bc2 = (const float*)d_in[8];
  float* out = (float*)d_out;

  char* ws = (char*)d_ws;
  f16*  Xg   = (f16*)(ws);                          // 64*1024*512*2  = 67108864 B
  f16*  y1h  = (f16*)(ws + 67108864);               // 64*1024*256*2  = 33554432 B
  f16*  Wx1T = (f16*)(ws + 100663296);              // 512*128*2      = 131072 B
  f16*  Wx2T = (f16*)(ws + 100794368);              // 512*256*2      = 262144 B
  f16*  UT1  = (f16*)(ws + 101056512);              // 512*256*2      = 262144 B
  f16*  UT2  = (f16*)(ws + 101318656);              // 512*256*2      = 262144 B
  int*  sync = (int*)(ws + 101580800);              // 36 ints (progress + done)

  float* y2   = out;                                // [64,1024,256]
  float* hid1 = out + (size_t)B_ * T_ * H_;         // [64,256]
  float* hid2 = hid1 + (size_t)B_ * H_;             // [64,256]

  prep_wxt<128><<<256, 256, 0, stream>>>(Wf1, Wc1, Wx1T);
  prep_wxt<256><<<512, 256, 0, stream>>>(Wf2, Wc2, Wx2T);
  prep_ut<<<512, 256, 0, stream>>>(Wf1, Wc1, UT1, 128);
  prep_ut<<<512, 256, 0, stream>>>(Wf2, Wc2, UT2, 256);
  init_sync<<<1, 64, 0, stream>>>(sync);

  gemm_xpart<128, true ><<<dim3(512, 4), 256, 0, stream>>>(x, Wx1T, bf1, bc1, Xg);
  fused<<<136, 512, 0, stream>>>(UT1, UT2, Xg, Wx2T, bf2, bc2, y1h, y2, hid1, hid2, sync);
}

// Round 10
// 1795.479 us; speedup vs baseline: 1.3471x; 1.3471x over previous
//
#include <hip/hip_runtime.h>

typedef unsigned int uint;
typedef _Float16 f16;
typedef _Float16 f16x2 __attribute__((ext_vector_type(2)));
typedef _Float16 f16x4 __attribute__((ext_vector_type(4)));
typedef _Float16 f16x8 __attribute__((ext_vector_type(8)));
typedef float f32x4 __attribute__((ext_vector_type(4)));

#define B_ 64
#define T_ 1024
#define I_ 128
#define H_ 256

// ---------------- prep: transpose x-part weights to [512 cols][K] fp16 ----------------
template<int KIN>
__global__ void prep_wxt(const float* __restrict__ Wf, const float* __restrict__ Wc,
                         f16* __restrict__ WxT) {
  int o = blockIdx.x * 256 + threadIdx.x;
  if (o >= 512 * KIN) return;
  int n = o / KIN, k = o % KIN;
  float v = (n < 256) ? Wf[k * H_ + n] : Wc[k * H_ + (n - 256)];
  WxT[o] = (f16)v;
}

// ---------------- prep: transpose recurrent weights to UT[512 n][256 k] fp16 ----------
__global__ void prep_ut(const float* __restrict__ Wf, const float* __restrict__ Wc,
                        f16* __restrict__ UT, int DIN) {
  int o = blockIdx.x * 256 + threadIdx.x;   // 512*256 = 131072
  int n = o >> 8, k = o & 255;
  const float* W = (n < 256) ? Wf : Wc;
  UT[o] = (f16)W[(DIN + k) * H_ + (n & 255)];
}

// ---------------- zero the sync counters (progress[4] + done[4][32]) ------------------
__global__ void init_sync(int* s) { if (threadIdx.x < 132) s[threadIdx.x] = 0; }

// ---------------- x-part GEMM (layer 1, fp32 A): Xg[m][512] = x @ Wx1T^T + bias -------
template<int KFULL, bool AF32>
__global__ __launch_bounds__(256) void gemm_xpart(const void* __restrict__ Av,
    const f16* __restrict__ Bt, const float* __restrict__ bf, const float* __restrict__ bc,
    f16* __restrict__ Xg) {
  __shared__ __align__(16) f16 As[128][72];
  __shared__ __align__(16) f16 Bs[128][72];
  const int m0 = blockIdx.x * 128, n0 = blockIdx.y * 128;
  const int tid = threadIdx.x, lane = tid & 63, wid = tid >> 6;
  const int wr = wid >> 1, wc = wid & 1;
  f32x4 zero4 = {0.f, 0.f, 0.f, 0.f};
  f32x4 acc[4][4];
  #pragma unroll
  for (int i = 0; i < 4; ++i)
    #pragma unroll
    for (int j = 0; j < 4; ++j) acc[i][j] = zero4;
  const int r2 = tid >> 1, hh = tid & 1;
  for (int kb = 0; kb < KFULL / 64; ++kb) {
    const int k0 = kb * 64;
    if (kb) __syncthreads();
    if (AF32) {
      const float* A = (const float*)Av;
      const float* src = A + (size_t)(m0 + r2) * KFULL + k0 + hh * 32;
      #pragma unroll
      for (int i = 0; i < 8; ++i) {
        float4 v = *(const float4*)(src + i * 4);
        f16x4 p = { (f16)v.x, (f16)v.y, (f16)v.z, (f16)v.w };
        *(f16x4*)&As[r2][hh * 32 + i * 4] = p;
      }
    } else {
      const f16* A = (const f16*)Av;
      const f16* src = A + (size_t)(m0 + r2) * KFULL + k0 + hh * 32;
      #pragma unroll
      for (int i = 0; i < 4; ++i)
        *(uint4*)&As[r2][hh * 32 + i * 8] = *(const uint4*)(src + i * 8);
    }
    {
      const f16* src = Bt + (size_t)(n0 + r2) * KFULL + k0 + hh * 32;
      #pragma unroll
      for (int i = 0; i < 4; ++i)
        *(uint4*)&Bs[r2][hh * 32 + i * 8] = *(const uint4*)(src + i * 8);
    }
    __syncthreads();
    #pragma unroll
    for (int kt = 0; kt < 2; ++kt) {
      f16x8 af[4], bfr[4];
      #pragma unroll
      for (int i = 0; i < 4; ++i)
        af[i] = *(const f16x8*)&As[wr * 64 + i * 16 + (lane & 15)][kt * 32 + (lane >> 4) * 8];
      #pragma unroll
      for (int j = 0; j < 4; ++j)
        bfr[j] = *(const f16x8*)&Bs[wc * 64 + j * 16 + (lane & 15)][kt * 32 + (lane >> 4) * 8];
      #pragma unroll
      for (int i = 0; i < 4; ++i)
        #pragma unroll
        for (int j = 0; j < 4; ++j)
          acc[i][j] = __builtin_amdgcn_mfma_f32_16x16x32_f16(af[i], bfr[j], acc[i][j], 0, 0, 0);
    }
  }
  const float* bias = (n0 < 256) ? bf : bc;
  #pragma unroll
  for (int j = 0; j < 4; ++j) {
    const int gn = n0 + wc * 64 + j * 16 + (lane & 15);
    const float bv = bias[gn & 255];
    #pragma unroll
    for (int i = 0; i < 4; ++i) {
      #pragma unroll
      for (int reg = 0; reg < 4; ++reg) {
        const int gm = m0 + wr * 64 + i * 16 + (lane >> 4) * 4 + reg;
        Xg[(size_t)gm * 512 + gn] = (f16)(acc[i][j][reg] + bv);
      }
    }
  }
}

// ---------------- device: one 32x128 Xg2 GEMM tile (R8 structure, smaller M) ----------
// A = y1h (f16, K=256), B = Wx2T.  256 staging threads, 4 MFMA waves (R8-proven).
// M=32 -> chunk quantum = 32 timesteps: pipeline lag 161us -> ~40us.
__device__ __forceinline__ void gemm_tile_l2(const f16* __restrict__ A,
    const f16* __restrict__ Bt, const float* __restrict__ bf, const float* __restrict__ bc,
    f16* __restrict__ Xg, int m0, int n0, f16 (*As)[72], f16 (*Bs)[72]) {
  const int tid = threadIdx.x, lane = tid & 63, wid = tid >> 6;
  const bool act = tid < 256;
  f32x4 zero4 = {0.f, 0.f, 0.f, 0.f};
  f32x4 acc[2][2];
  #pragma unroll
  for (int i = 0; i < 2; ++i)
    #pragma unroll
    for (int j = 0; j < 2; ++j) acc[i][j] = zero4;
  const int arow = tid >> 3, aq = tid & 7;          // A: 32 rows x 8 col-slices
  const int r2 = (tid & 255) >> 1, hh = tid & 1;    // B: as R8
  for (int kb = 0; kb < 4; ++kb) {
    const int k0 = kb * 64;
    if (kb) __syncthreads();
    if (act) {
      const f16* srcA = A + (size_t)(m0 + arow) * 256 + k0 + aq * 8;
      *(uint4*)&As[arow][aq * 8] = *(const uint4*)srcA;
      const f16* srcB = Bt + (size_t)(n0 + r2) * 256 + k0 + hh * 32;
      #pragma unroll
      for (int i = 0; i < 4; ++i)
        *(uint4*)&Bs[r2][hh * 32 + i * 8] = *(const uint4*)(srcB + i * 8);
    }
    __syncthreads();
    if (wid < 4) {
      #pragma unroll
      for (int kt = 0; kt < 2; ++kt) {
        f16x8 af[2], bfr[2];
        #pragma unroll
        for (int i = 0; i < 2; ++i)
          af[i] = *(const f16x8*)&As[i * 16 + (lane & 15)][kt * 32 + (lane >> 4) * 8];
        #pragma unroll
        for (int j = 0; j < 2; ++j)
          bfr[j] = *(const f16x8*)&Bs[wid * 32 + j * 16 + (lane & 15)][kt * 32 + (lane >> 4) * 8];
        #pragma unroll
        for (int i = 0; i < 2; ++i)
          #pragma unroll
          for (int j = 0; j < 2; ++j)
            acc[i][j] = __builtin_amdgcn_mfma_f32_16x16x32_f16(af[i], bfr[j], acc[i][j], 0, 0, 0);
      }
    }
  }
  if (wid < 4) {
    const float* bias = (n0 < 256) ? bf : bc;
    #pragma unroll
    for (int j = 0; j < 2; ++j) {
      const int gn = n0 + wid * 32 + j * 16 + (lane & 15);
      const float bv = bias[gn & 255];
      #pragma unroll
      for (int i = 0; i < 2; ++i) {
        #pragma unroll
        for (int reg = 0; reg < 4; ++reg) {
          const int gm = m0 + i * 16 + (lane >> 4) * 4 + reg;
          Xg[(size_t)gm * 512 + gn] = (f16)(acc[i][j][reg] + bv);
        }
      }
    }
  }
  __syncthreads();   // As/Bs safe for next tile
}

// ---------------- device: R6 rec inner loop + optional publish/gate (R8-proven) -------
// prog_pub (L1): publish t+1 every 32 steps.  done_gate (L2): before consuming Xg
// chunk c (32 steps), wait done[c]==64.
__device__ __forceinline__ void rec_core(const f16* __restrict__ UT,
    f16* __restrict__ Xg, float* __restrict__ yf, f16* __restrict__ yh,
    float* __restrict__ hid, const int g, int* prog_pub, int* done_gate,
    f16 (*hbuf)[16][264]) {
  const int tid = threadIdx.x;
  const int lane = tid & 63, w = tid >> 6;
  const int lr = lane & 15, lg = lane >> 4;
  const int m0 = g * 16;

  const int nt[4] = { 32 * w, 32 * w + 16, 256 + 32 * w, 256 + 32 * w + 16 };

  f16x8 uw[4][8];
  #pragma unroll
  for (int tt = 0; tt < 4; ++tt)
    #pragma unroll
    for (int kf = 0; kf < 8; ++kf)
      uw[tt][kf] = *(const f16x8*)&UT[(size_t)(nt[tt] + lr) * 256 + kf * 32 + lg * 8];
  #pragma unroll
  for (int tt = 0; tt < 4; ++tt)
    #pragma unroll
    for (int kf = 0; kf < 8; ++kf)
      asm volatile("" : "+v"(uw[tt][kf]));

  {
    uint* hz = (uint*)&hbuf[0][0][0];
    for (int i = tid; i < 2112; i += 512) hz[i] = 0u;
  }

  // L2 role: Xg chunk 0 must be written before the first reads
  if (done_gate) {
    if (tid == 0)
      while (__hip_atomic_load(&done_gate[0], __ATOMIC_ACQUIRE, __HIP_MEMORY_SCOPE_AGENT) < 64)
        __builtin_amdgcn_s_sleep(8);
    __syncthreads();
  }

  const f16* xp[4];
  #pragma unroll
  for (int tt = 0; tt < 4; ++tt)
    xp[tt] = Xg + ((size_t)(m0 + lr) * T_) * 512 + nt[tt] + 4 * lg;

  float hreg[2][4] = {{0.f,0.f,0.f,0.f},{0.f,0.f,0.f,0.f}};
  f16x4 xcur[4];
  #pragma unroll
  for (int tt = 0; tt < 4; ++tt) xcur[tt] = *(const f16x4*)xp[tt];

  const size_t ybase = (size_t)(m0 + lr) * T_ * H_;
  const int ycol0 = 32 * w + 4 * lg;

  __syncthreads();

  #pragma unroll 1
  for (int t = 0; t < T_; ++t) {
    // L2 role: gate the NEXT 32-step chunk before prefetching into it
    if (done_gate) {
      const int tp1 = t + 1;
      if ((tp1 & 31) == 0 && (tp1 >> 5) < 32) {
        if (tid == 0)
          while (__hip_atomic_load(&done_gate[tp1 >> 5], __ATOMIC_ACQUIRE, __HIP_MEMORY_SCOPE_AGENT) < 64)
            __builtin_amdgcn_s_sleep(8);
        __syncthreads();
      }
    }

    const int tn = (t + 1 < T_) ? t + 1 : t;
    f16x4 xn[4];
    #pragma unroll
    for (int tt = 0; tt < 4; ++tt) xn[tt] = *(const f16x4*)(xp[tt] + (size_t)tn * 512);

    const f16* hrow = &hbuf[t & 1][lr][0];
    f16x8 hf[8];
    #pragma unroll
    for (int kf = 0; kf < 8; ++kf)
      hf[kf] = *(const f16x8*)(hrow + kf * 32 + lg * 8);

    f32x4 acc[4];
    #pragma unroll
    for (int tt = 0; tt < 4; ++tt) acc[tt] = (f32x4){0.f, 0.f, 0.f, 0.f};
    #pragma unroll
    for (int kf = 0; kf < 8; ++kf)
      #pragma unroll
      for (int tt = 0; tt < 4; ++tt)
        acc[tt] = __builtin_amdgcn_mfma_f32_16x16x32_f16(uw[tt][kf], hf[kf], acc[tt], 0, 0, 0);

    f16x4 hn4[2];
    #pragma unroll
    for (int p = 0; p < 2; ++p) {
      #pragma unroll
      for (int r = 0; r < 4; ++r) {
        float pf = acc[p][r]     + (float)xcur[p][r];
        float pc = acc[2 + p][r] + (float)xcur[2 + p][r];
        float fg = __builtin_amdgcn_rcpf(1.f + __expf(-pf));
        float e2 = __expf(2.f * pc);
        float cc = 1.f - 2.f * __builtin_amdgcn_rcpf(e2 + 1.f);
        float hn = cc + fg * (hreg[p][r] - cc);
        hreg[p][r] = hn;
        hn4[p][r] = (f16)hn;
      }
      *(f16x4*)&hbuf[(t + 1) & 1][lr][ycol0 + 16 * p] = hn4[p];
    }
    if (yh) {
      #pragma unroll
      for (int p = 0; p < 2; ++p)
        *(f16x4*)(yh + ybase + (size_t)t * H_ + ycol0 + 16 * p) = hn4[p];
    }
    if (yf) {
      #pragma unroll
      for (int p = 0; p < 2; ++p) {
        float4 yv = make_float4(hreg[p][0], hreg[p][1], hreg[p][2], hreg[p][3]);
        *(float4*)(yf + ybase + (size_t)t * H_ + ycol0 + 16 * p) = yv;
      }
    }
    if (t == T_ - 1) {
      #pragma unroll
      for (int p = 0; p < 2; ++p) {
        float4 hv = make_float4(hreg[p][0], hreg[p][1], hreg[p][2], hreg[p][3]);
        *(float4*)(hid + (size_t)(m0 + lr) * H_ + ycol0 + 16 * p) = hv;
      }
    }

    asm volatile("s_waitcnt lgkmcnt(0)" ::: "memory");
    __builtin_amdgcn_s_barrier();
    asm volatile("" ::: "memory");

    // L1 role: publish progress (y1h through step t now globally visible)
    if (prog_pub && ((t & 31) == 31)) {
      asm volatile("s_waitcnt vmcnt(0)" ::: "memory");
      __syncthreads();
      if (tid == 0)
        __hip_atomic_store(prog_pub, t + 1, __ATOMIC_RELEASE, __HIP_MEMORY_SCOPE_AGENT);
    }

    #pragma unroll
    for (int tt = 0; tt < 4; ++tt) xcur[tt] = xn[tt];
  }
}

// ---------------- fused pipeline: 4 L1-rec + 64 GEMM workers + 4 L2-rec ---------------
// R8 structure (64 workers proven; R9's 128 workers + 8-wave tile regressed 27% from
// contention).  Chunk quantum shrunk 128->32 steps via 32-row tiles: L2's structural
// trailing lag drops ~160us.  Worker wk per chunk c: 4 tiles tau = wk + 64j,
// j = 4c..4c+3 (one tile per batch-group).  done[g][c] target = 16b x 4n = 64.
__global__ __launch_bounds__(512, 1) void fused(const f16* __restrict__ UT1,
    const f16* __restrict__ UT2, f16* __restrict__ Xg, const f16* __restrict__ Wx2T,
    const float* __restrict__ bf2, const float* __restrict__ bc2,
    f16* __restrict__ y1h, float* __restrict__ y2,
    float* __restrict__ hid1, float* __restrict__ hid2, int* __restrict__ sync) {
  __shared__ __align__(16) f16 hbuf[2][16][264];
  __shared__ __align__(16) f16 As[32][72];
  __shared__ __align__(16) f16 Bs[128][72];
  int* prog = sync;        // [4]   L1 step progress per row-group
  int* done = sync + 4;    // [4][32] finished Xg2 tiles per (group, 32-step chunk)
  const int bid = blockIdx.x, tid = threadIdx.x;

  if (bid < 4) {
    rec_core(UT1, Xg, nullptr, y1h, hid1, bid, &prog[bid], nullptr, hbuf);
  } else if (bid < 68) {
    const int wk = bid - 4;                        // 0..63
    for (int j = 0; j < 128; ++j) {
      const int tau = wk + 64 * j;                 // chunk-major tile order
      const int c = tau >> 8, rem = tau & 255, b = rem >> 2, n = rem & 3;
      const int g1 = b >> 4;
      if (tid == 0)
        while (__hip_atomic_load(&prog[g1], __ATOMIC_ACQUIRE, __HIP_MEMORY_SCOPE_AGENT) < c * 32 + 32)
          __builtin_amdgcn_s_sleep(8);
      __syncthreads();
      gemm_tile_l2(y1h, Wx2T, bf2, bc2, Xg, b * 1024 + c * 32, n * 128, As, Bs);
      asm volatile("s_waitcnt vmcnt(0)" ::: "memory");
      __syncthreads();
      if (tid == 0)
        __hip_atomic_fetch_add(&done[g1 * 32 + c], 1, __ATOMIC_ACQ_REL, __HIP_MEMORY_SCOPE_AGENT);
    }
  } else {
    const int g = bid - 68;
    rec_core(UT2, Xg, y2, nullptr, hid2, g, nullptr, &done[g * 32], hbuf);
  }
}

extern "C" void kernel_launch(void* const* d_in, const int* in_sizes, int n_in,
                              void* d_out, int out_size, void* d_ws, size_t ws_size,
                              hipStream_t stream) {
  (void)in_sizes; (void)n_in; (void)out_size; (void)ws_size;
  const float* x   = (const float*)d_in[0];
  const float* Wf1 = (const float*)d_in[1];
  const float* bf1 = (const float*)d_in[2];
  const float* Wc1 = (const float*)d_in[3];
  const float* bc1 = (const float*)d_in[4];
  const float* Wf2 = (const float*)d_in[5];
  const float* bf2 = (const float*)d_in[6];
  const float* Wc2 = (const float*)d_in[7];
  const float* bc2 = (const float*)d_in[8];
  float* out = (float*)d_out;

  char* ws = (char*)d_ws;
  f16*  Xg   = (f16*)(ws);                          // 64*1024*512*2  = 67108864 B
  f16*  y1h  = (f16*)(ws + 67108864);               // 64*1024*256*2  = 33554432 B
  f16*  Wx1T = (f16*)(ws + 100663296);              // 512*128*2      = 131072 B
  f16*  Wx2T = (f16*)(ws + 100794368);              // 512*256*2      = 262144 B
  f16*  UT1  = (f16*)(ws + 101056512);              // 512*256*2      = 262144 B
  f16*  UT2  = (f16*)(ws + 101318656);              // 512*256*2      = 262144 B
  int*  sync = (int*)(ws + 101580800);              // 132 ints (progress + done)

  float* y2   = out;                                // [64,1024,256]
  float* hid1 = out + (size_t)B_ * T_ * H_;         // [64,256]
  float* hid2 = hid1 + (size_t)B_ * H_;             // [64,256]

  prep_wxt<128><<<256, 256, 0, stream>>>(Wf1, Wc1, Wx1T);
  prep_wxt<256><<<512, 256, 0, stream>>>(Wf2, Wc2, Wx2T);
  prep_ut<<<512, 256, 0, stream>>>(Wf1, Wc1, UT1, 128);
  prep_ut<<<512, 256, 0, stream>>>(Wf2, Wc2, UT2, 256);
  init_sync<<<1, 256, 0, stream>>>(sync);

  gemm_xpart<128, true ><<<dim3(512, 4), 256, 0, stream>>>(x, Wx1T, bf1, bc1, Xg);
  fused<<<72, 512, 0, stream>>>(UT1, UT2, Xg, Wx2T, bf2, bc2, y1h, y2, hid1, hid2, sync);
}